// Round 1
// baseline (186.525 us; speedup 1.0000x reference)
//
#include <hip/hip_runtime.h>

#define B_ 4
#define N_ 7
#define L_ 512
#define S_ 512
#define H_ 8
#define E_ 64
#define D_ 64

constexpr int QT = 128;       // Q rows per block
constexpr int ST = 128;       // S rows per LDS tile
constexpr int KP = 72;        // K LDS row pitch (f16 elems) -> 144B, conflict-free b128 reads
constexpr int VP = ST + 4;    // Vt LDS row pitch = 132 -> 264B, conflict-free b64 reads

typedef _Float16 f16x8 __attribute__((ext_vector_type(8)));
typedef _Float16 f16x4 __attribute__((ext_vector_type(4)));
typedef float    f32x4 __attribute__((ext_vector_type(4)));

__global__ __launch_bounds__(256)
void attn_fwd(const float* __restrict__ Q, const float* __restrict__ K,
              const float* __restrict__ V, float* __restrict__ O)
{
    __shared__ _Float16 Ks[ST * KP];   // K tile, row-major [s][e]
    __shared__ _Float16 Vs[D_ * VP];   // V tile transposed [d][s]

    const int bnh   = blockIdx.y;              // 0..223
    const int h     = bnh & (H_ - 1);
    const int bn    = bnh >> 3;
    const int qbase = blockIdx.x * QT;

    const int tid  = threadIdx.x;
    const int wid  = tid >> 6;                 // wave id 0..3, owns Q rows [wid*32, wid*32+32)
    const int lane = tid & 63;
    const int quad = lane >> 4;
    const int m16  = lane & 15;

    const float* Qp = Q + ((size_t)bn * L_ * H_ + h) * E_;
    const float* Kp = K + ((size_t)bn * S_ * H_ + h) * E_;
    const float* Vp = V + ((size_t)bn * S_ * H_ + h) * D_;
    float*       Op = O + ((size_t)bn * L_ * H_ + h) * D_;

    // ---- Q fragments (B-operand of St = K*Q^T), scale 1/sqrt(E)*log2(e) folded in ----
    const float qsc = 0.125f * 1.4426950408889634f;
    f16x8 qf[2][2];
    #pragma unroll
    for (int lt = 0; lt < 2; ++lt)
        #pragma unroll
        for (int kt = 0; kt < 2; ++kt) {
            const float* p = Qp + (size_t)(qbase + wid*32 + lt*16 + m16) * (H_*E_)
                                + kt*32 + quad*8;
            float4 a = *(const float4*)p;
            float4 b = *(const float4*)(p + 4);
            f16x8 f;
            f[0]=(_Float16)(a.x*qsc); f[1]=(_Float16)(a.y*qsc);
            f[2]=(_Float16)(a.z*qsc); f[3]=(_Float16)(a.w*qsc);
            f[4]=(_Float16)(b.x*qsc); f[5]=(_Float16)(b.y*qsc);
            f[6]=(_Float16)(b.z*qsc); f[7]=(_Float16)(b.w*qsc);
            qf[lt][kt] = f;
        }

    const f32x4 fzero = {0.f, 0.f, 0.f, 0.f};
    f32x4 of[2][4];
    #pragma unroll
    for (int lt = 0; lt < 2; ++lt)
        #pragma unroll
        for (int dt = 0; dt < 4; ++dt) of[lt][dt] = fzero;

    float m_run[2] = {-1e30f, -1e30f};
    float l_run[2] = {0.f, 0.f};

    for (int sb = 0; sb < S_; sb += ST) {
        __syncthreads();   // protect LDS tiles from prior-iteration readers

        // ---- stage K tile: coalesced float4 rows -> f16x4 LDS writes ----
        #pragma unroll
        for (int j = 0; j < 8; ++j) {
            int idx = j*256 + tid;
            int r = idx >> 4, c = (idx & 15) * 4;
            float4 v = *(const float4*)(Kp + (size_t)(sb + r)*(H_*E_) + c);
            f16x4 w;
            w[0]=(_Float16)v.x; w[1]=(_Float16)v.y; w[2]=(_Float16)v.z; w[3]=(_Float16)v.w;
            *(f16x4*)&Ks[r*KP + c] = w;
        }
        // ---- stage V transposed: coalesced float4 rows -> 4 scalar column writes ----
        #pragma unroll
        for (int j = 0; j < 8; ++j) {
            int idx = j*256 + tid;
            int r = idx >> 4, d = (idx & 15) * 4;
            float4 v = *(const float4*)(Vp + (size_t)(sb + r)*(H_*D_) + d);
            Vs[(d+0)*VP + r] = (_Float16)v.x;
            Vs[(d+1)*VP + r] = (_Float16)v.y;
            Vs[(d+2)*VP + r] = (_Float16)v.z;
            Vs[(d+3)*VP + r] = (_Float16)v.w;
        }
        __syncthreads();

        // ---- St = K*Q^T : C-layout value = score(l = lt*16+m16, s = st*16+quad*4+reg) ----
        f32x4 acc[8][2];
        #pragma unroll
        for (int st = 0; st < 8; ++st) { acc[st][0] = fzero; acc[st][1] = fzero; }
        #pragma unroll
        for (int st = 0; st < 8; ++st) {
            #pragma unroll
            for (int kt = 0; kt < 2; ++kt) {
                f16x8 kf = *(const f16x8*)&Ks[(st*16 + m16)*KP + kt*32 + quad*8];
                acc[st][0] = __builtin_amdgcn_mfma_f32_16x16x32_f16(kf, qf[0][kt], acc[st][0], 0,0,0);
                acc[st][1] = __builtin_amdgcn_mfma_f32_16x16x32_f16(kf, qf[1][kt], acc[st][1], 0,0,0);
            }
        }

        // ---- online softmax, per Q-row (= St column, keyed by m16) ----
        #pragma unroll
        for (int lt = 0; lt < 2; ++lt) {
            float mt = -1e30f;
            #pragma unroll
            for (int st = 0; st < 8; ++st)
                mt = fmaxf(mt, fmaxf(fmaxf(acc[st][lt][0], acc[st][lt][1]),
                                     fmaxf(acc[st][lt][2], acc[st][lt][3])));
            mt = fmaxf(mt, __shfl_xor(mt, 16));
            mt = fmaxf(mt, __shfl_xor(mt, 32));
            float mnew  = fmaxf(m_run[lt], mt);
            float alpha = exp2f(m_run[lt] - mnew);
            float rsum = 0.f;
            #pragma unroll
            for (int st = 0; st < 8; ++st)
                #pragma unroll
                for (int r = 0; r < 4; ++r) {
                    float p = exp2f(acc[st][lt][r] - mnew);
                    acc[st][lt][r] = p;
                    rsum += p;
                }
            rsum += __shfl_xor(rsum, 16);
            rsum += __shfl_xor(rsum, 32);
            l_run[lt] = l_run[lt] * alpha + rsum;
            m_run[lt] = mnew;
            // rescale O: O-row l = lt*16 + quad*4 + r, its alpha lives at lane (quad*4+r)
            #pragma unroll
            for (int r = 0; r < 4; ++r) {
                float aO = __shfl(alpha, quad*4 + r);
                #pragma unroll
                for (int dt = 0; dt < 4; ++dt) of[lt][dt][r] *= aO;
            }
        }

        // ---- O += P*V : P is already in 16x16x16 A-operand layout in registers ----
        #pragma unroll
        for (int st = 0; st < 8; ++st) {
            f16x4 vf[4];
            #pragma unroll
            for (int dt = 0; dt < 4; ++dt)
                vf[dt] = *(const f16x4*)&Vs[(dt*16 + m16)*VP + st*16 + quad*4];
            #pragma unroll
            for (int lt = 0; lt < 2; ++lt) {
                f16x4 pf;
                pf[0]=(_Float16)acc[st][lt][0]; pf[1]=(_Float16)acc[st][lt][1];
                pf[2]=(_Float16)acc[st][lt][2]; pf[3]=(_Float16)acc[st][lt][3];
                #pragma unroll
                for (int dt = 0; dt < 4; ++dt)
                    of[lt][dt] = __builtin_amdgcn_mfma_f32_16x16x16f16(pf, vf[dt], of[lt][dt], 0,0,0);
            }
        }
    }

    // ---- epilogue: normalize by l_run and store (16-lane 64B contiguous chunks) ----
    #pragma unroll
    for (int lt = 0; lt < 2; ++lt)
        #pragma unroll
        for (int r = 0; r < 4; ++r) {
            float inv = 1.0f / __shfl(l_run[lt], quad*4 + r);
            float* op = Op + (size_t)(qbase + wid*32 + lt*16 + quad*4 + r)*(H_*D_) + m16;
            #pragma unroll
            for (int dt = 0; dt < 4; ++dt)
                op[dt*16] = of[lt][dt][r] * inv;
        }
}

extern "C" void kernel_launch(void* const* d_in, const int* in_sizes, int n_in,
                              void* d_out, int out_size, void* d_ws, size_t ws_size,
                              hipStream_t stream)
{
    const float* Q = (const float*)d_in[0];
    const float* K = (const float*)d_in[1];
    const float* V = (const float*)d_in[2];
    float* O = (float*)d_out;
    dim3 grid(L_ / QT, B_ * N_ * H_);   // (4 q-tiles, 224 batch-heads)
    attn_fwd<<<grid, 256, 0, stream>>>(Q, K, V, O);
}

// Round 2
// 159.645 us; speedup vs baseline: 1.1684x; 1.1684x over previous
//
#include <hip/hip_runtime.h>

#define B_ 4
#define N_ 7
#define L_ 512
#define S_ 512
#define H_ 8
#define E_ 64
#define D_ 64

constexpr int QT = 128;       // Q rows per block (8 waves x 16 rows)
constexpr int ST = 128;       // S rows per LDS tile
constexpr int KP = 72;        // K LDS row pitch (f16) -> 144B, conflict-light b128 reads
constexpr int VP = ST + 4;    // Vt LDS row pitch = 132

typedef _Float16 f16x8 __attribute__((ext_vector_type(8)));
typedef _Float16 f16x4 __attribute__((ext_vector_type(4)));
typedef float    f32x4 __attribute__((ext_vector_type(4)));

// 512 threads, min 4 waves/EU -> VGPR cap 128 -> 16 waves/CU
__global__ __launch_bounds__(512, 4)
void attn_fwd(const float* __restrict__ Q, const float* __restrict__ K,
              const float* __restrict__ V, float* __restrict__ O)
{
    __shared__ _Float16 Ks[ST * KP];   // K tile, row-major [s][e]
    __shared__ _Float16 Vs[D_ * VP];   // V tile transposed [d][s]

    const int bnh   = blockIdx.y;              // 0..223
    const int h     = bnh & (H_ - 1);
    const int bn    = bnh >> 3;
    const int qbase = blockIdx.x * QT;

    const int tid  = threadIdx.x;
    const int wid  = tid >> 6;                 // wave id 0..7, owns Q rows [wid*16, wid*16+16)
    const int lane = tid & 63;
    const int quad = lane >> 4;
    const int m16  = lane & 15;

    const float* Qp = Q + ((size_t)bn * L_ * H_ + h) * E_;
    const float* Kp = K + ((size_t)bn * S_ * H_ + h) * E_;
    const float* Vp = V + ((size_t)bn * S_ * H_ + h) * D_;
    float*       Op = O + ((size_t)bn * L_ * H_ + h) * E_;

    // ---- Q fragments (B-operand of St = K*Q^T), scale 1/sqrt(E)*log2(e) folded ----
    const float qsc = 0.125f * 1.4426950408889634f;
    f16x8 qf[2];
    #pragma unroll
    for (int kt = 0; kt < 2; ++kt) {
        const float* p = Qp + (size_t)(qbase + wid*16 + m16) * (H_*E_) + kt*32 + quad*8;
        float4 a = *(const float4*)p;
        float4 b = *(const float4*)(p + 4);
        f16x8 f;
        f[0]=(_Float16)(a.x*qsc); f[1]=(_Float16)(a.y*qsc);
        f[2]=(_Float16)(a.z*qsc); f[3]=(_Float16)(a.w*qsc);
        f[4]=(_Float16)(b.x*qsc); f[5]=(_Float16)(b.y*qsc);
        f[6]=(_Float16)(b.z*qsc); f[7]=(_Float16)(b.w*qsc);
        qf[kt] = f;
    }

    const f32x4 fzero = {0.f, 0.f, 0.f, 0.f};
    f32x4 of[4];
    #pragma unroll
    for (int dt = 0; dt < 4; ++dt) of[dt] = fzero;

    float m_run = -1e30f;
    float l_run = 0.f;

    for (int sb = 0; sb < S_; sb += ST) {
        __syncthreads();   // protect LDS tiles from prior-iteration readers

        // ---- stage K tile: 512 threads x 4 float4 rows -> f16x4 LDS writes ----
        #pragma unroll
        for (int j = 0; j < 4; ++j) {
            int idx = j*512 + tid;
            int r = idx >> 4, c = (idx & 15) * 4;
            float4 v = *(const float4*)(Kp + (size_t)(sb + r)*(H_*E_) + c);
            f16x4 w;
            w[0]=(_Float16)v.x; w[1]=(_Float16)v.y; w[2]=(_Float16)v.z; w[3]=(_Float16)v.w;
            *(f16x4*)&Ks[r*KP + c] = w;
        }
        // ---- stage V transposed: coalesced float4 rows -> 4 scalar column writes ----
        #pragma unroll
        for (int j = 0; j < 4; ++j) {
            int idx = j*512 + tid;
            int r = idx >> 4, d = (idx & 15) * 4;
            float4 v = *(const float4*)(Vp + (size_t)(sb + r)*(H_*D_) + d);
            Vs[(d+0)*VP + r] = (_Float16)v.x;
            Vs[(d+1)*VP + r] = (_Float16)v.y;
            Vs[(d+2)*VP + r] = (_Float16)v.z;
            Vs[(d+3)*VP + r] = (_Float16)v.w;
        }
        __syncthreads();

        // ---- St = K*Q^T : C value = score(l = m16, s = st*16 + quad*4 + reg) ----
        f32x4 acc[8];
        #pragma unroll
        for (int st = 0; st < 8; ++st) acc[st] = fzero;
        #pragma unroll
        for (int st = 0; st < 8; ++st) {
            #pragma unroll
            for (int kt = 0; kt < 2; ++kt) {
                f16x8 kf = *(const f16x8*)&Ks[(st*16 + m16)*KP + kt*32 + quad*8];
                acc[st] = __builtin_amdgcn_mfma_f32_16x16x32_f16(kf, qf[kt], acc[st], 0,0,0);
            }
        }

        // ---- online softmax, per Q-row (= St column, keyed by m16) ----
        {
            float mt = -1e30f;
            #pragma unroll
            for (int st = 0; st < 8; ++st)
                mt = fmaxf(mt, fmaxf(fmaxf(acc[st][0], acc[st][1]),
                                     fmaxf(acc[st][2], acc[st][3])));
            mt = fmaxf(mt, __shfl_xor(mt, 16));
            mt = fmaxf(mt, __shfl_xor(mt, 32));
            float mnew  = fmaxf(m_run, mt);
            float alpha = exp2f(m_run - mnew);
            float rsum = 0.f;
            #pragma unroll
            for (int st = 0; st < 8; ++st)
                #pragma unroll
                for (int r = 0; r < 4; ++r) {
                    float p = exp2f(acc[st][r] - mnew);
                    acc[st][r] = p;
                    rsum += p;
                }
            rsum += __shfl_xor(rsum, 16);
            rsum += __shfl_xor(rsum, 32);
            l_run = l_run * alpha + rsum;
            m_run = mnew;
            // rescale O: O-row l = quad*4 + r, its alpha lives at lane (quad*4+r)
            #pragma unroll
            for (int r = 0; r < 4; ++r) {
                float aO = __shfl(alpha, quad*4 + r);
                #pragma unroll
                for (int dt = 0; dt < 4; ++dt) of[dt][r] *= aO;
            }
        }

        // ---- O += P*V : P (St C-layout) is already 16x16x16 A-operand layout ----
        #pragma unroll
        for (int st = 0; st < 8; ++st) {
            f16x4 pf;
            pf[0]=(_Float16)acc[st][0]; pf[1]=(_Float16)acc[st][1];
            pf[2]=(_Float16)acc[st][2]; pf[3]=(_Float16)acc[st][3];
            #pragma unroll
            for (int dt = 0; dt < 4; ++dt) {
                f16x4 vf = *(const f16x4*)&Vs[(dt*16 + m16)*VP + st*16 + quad*4];
                of[dt] = __builtin_amdgcn_mfma_f32_16x16x16f16(pf, vf, of[dt], 0,0,0);
            }
        }
    }

    // ---- epilogue: normalize by l_run and store (16-lane 64B contiguous chunks) ----
    #pragma unroll
    for (int r = 0; r < 4; ++r) {
        float inv = 1.0f / __shfl(l_run, quad*4 + r);
        float* op = Op + (size_t)(qbase + wid*16 + quad*4 + r)*(H_*D_) + m16;
        #pragma unroll
        for (int dt = 0; dt < 4; ++dt)
            op[dt*16] = of[dt][r] * inv;
    }
}

extern "C" void kernel_launch(void* const* d_in, const int* in_sizes, int n_in,
                              void* d_out, int out_size, void* d_ws, size_t ws_size,
                              hipStream_t stream)
{
    const float* Q = (const float*)d_in[0];
    const float* K = (const float*)d_in[1];
    const float* V = (const float*)d_in[2];
    float* O = (float*)d_out;
    dim3 grid(L_ / QT, B_ * N_ * H_);   // (4 q-tiles, 224 batch-heads)
    attn_fwd<<<grid, 512, 0, stream>>>(Q, K, V, O);
}